// Round 1
// baseline (1677.686 us; speedup 1.0000x reference)
//
#include <hip/hip_runtime.h>
#include <hip/hip_bf16.h>
#include <math.h>

// GGNN binary classifier: s=4096, N=4 nodes, 8 GRU steps, MLP head.
// Memory-bound on weight streaming: W_ih (402MB) + W_hh (201MB) per step x8,
// + fc1_w (268MB) once => ~5.1 GB fp32 => ~810us roofline at 6.3 TB/s.
//
// Layouts in workspace:
//   h state: float4[4096], h_t[k] = {h[0][k], h[1][k], h[2][k], h[3][k]}  (ping-pong A/B)
//   a_t:     float4[8192], a_t[k] = {a[0][k]..a[3][k]}  (a = [A_out@h, A_in@h])
//   enc:     float[16384]  (h.reshape(1,-1): enc[n*4096+k])
//   x1:      float[4096]

#define S 4096

__device__ __forceinline__ float wave_reduce_add(float v) {
#pragma unroll
    for (int off = 32; off > 0; off >>= 1) v += __shfl_down(v, off, 64);
    return v;
}

__global__ void init_h_k(const float* __restrict__ ann, float4* __restrict__ h) {
    int k = blockIdx.x * 256 + threadIdx.x;  // 0..4095
    float4 o;
    o.x = ann[k];
    o.y = ann[S + k];
    o.z = ann[2 * S + k];
    o.w = ann[3 * S + k];
    h[k] = o;
}

__global__ void compute_a_k(const float* __restrict__ Aout, const float* __restrict__ Ain,
                            const float4* __restrict__ h, float4* __restrict__ a) {
    int k = blockIdx.x * 256 + threadIdx.x;  // 0..8191
    const float* M = (k < S) ? Aout : Ain;
    int kk = k & (S - 1);
    float4 hv = h[kk];
    float4 o;
    o.x = M[0]  * hv.x + M[1]  * hv.y + M[2]  * hv.z + M[3]  * hv.w;
    o.y = M[4]  * hv.x + M[5]  * hv.y + M[6]  * hv.z + M[7]  * hv.w;
    o.z = M[8]  * hv.x + M[9]  * hv.y + M[10] * hv.z + M[11] * hv.w;
    o.w = M[12] * hv.x + M[13] * hv.y + M[14] * hv.z + M[15] * hv.w;
    a[k] = o;
}

// One block per output column c in [0,4096). Computes gate pre-activations for
// rows c (r), S+c (z), 2S+c (n) of both W_ih (K=8192) and W_hh (K=4096),
// for all 4 nodes, then applies the GRU cell and writes h_next[c].
__global__ __launch_bounds__(256) void gru_col_k(
    const float* __restrict__ Wih, const float* __restrict__ Whh,
    const float4* __restrict__ a, const float4* __restrict__ hcur,
    float4* __restrict__ hnext) {
    const int c = blockIdx.x;
    const int t = threadIdx.x;

    float accI[3][4];
    float accH[3][4];
#pragma unroll
    for (int g = 0; g < 3; g++)
#pragma unroll
        for (int n = 0; n < 4; n++) { accI[g][n] = 0.f; accH[g][n] = 0.f; }

    // W_ih rows (each 8192 floats = 2048 float4)
    const float4* Wi[3];
    Wi[0] = (const float4*)(Wih + (size_t)(0 * S + c) * (2 * S));
    Wi[1] = (const float4*)(Wih + (size_t)(1 * S + c) * (2 * S));
    Wi[2] = (const float4*)(Wih + (size_t)(2 * S + c) * (2 * S));

#pragma unroll 2
    for (int i = 0; i < 8; i++) {
        int j = t + 256 * i;          // float4 index in row, 0..2047
        int ka = 4 * j;               // scalar k
        float4 a0 = a[ka + 0];
        float4 a1 = a[ka + 1];
        float4 a2 = a[ka + 2];
        float4 a3 = a[ka + 3];
#pragma unroll
        for (int g = 0; g < 3; g++) {
            float4 w = Wi[g][j];
            accI[g][0] += w.x * a0.x + w.y * a1.x + w.z * a2.x + w.w * a3.x;
            accI[g][1] += w.x * a0.y + w.y * a1.y + w.z * a2.y + w.w * a3.y;
            accI[g][2] += w.x * a0.z + w.y * a1.z + w.z * a2.z + w.w * a3.z;
            accI[g][3] += w.x * a0.w + w.y * a1.w + w.z * a2.w + w.w * a3.w;
        }
    }

    // W_hh rows (each 4096 floats = 1024 float4)
    const float4* Wh[3];
    Wh[0] = (const float4*)(Whh + (size_t)(0 * S + c) * S);
    Wh[1] = (const float4*)(Whh + (size_t)(1 * S + c) * S);
    Wh[2] = (const float4*)(Whh + (size_t)(2 * S + c) * S);

#pragma unroll 2
    for (int i = 0; i < 4; i++) {
        int j = t + 256 * i;          // 0..1023
        int ka = 4 * j;
        float4 h0 = hcur[ka + 0];
        float4 h1 = hcur[ka + 1];
        float4 h2 = hcur[ka + 2];
        float4 h3 = hcur[ka + 3];
#pragma unroll
        for (int g = 0; g < 3; g++) {
            float4 w = Wh[g][j];
            accH[g][0] += w.x * h0.x + w.y * h1.x + w.z * h2.x + w.w * h3.x;
            accH[g][1] += w.x * h0.y + w.y * h1.y + w.z * h2.y + w.w * h3.y;
            accH[g][2] += w.x * h0.z + w.y * h1.z + w.z * h2.z + w.w * h3.z;
            accH[g][3] += w.x * h0.w + w.y * h1.w + w.z * h2.w + w.w * h3.w;
        }
    }

    // Block reduction of 24 partials
    __shared__ float red[4][24];
    int lane = t & 63, wid = t >> 6;
#pragma unroll
    for (int g = 0; g < 3; g++) {
#pragma unroll
        for (int n = 0; n < 4; n++) {
            float vI = wave_reduce_add(accI[g][n]);
            float vH = wave_reduce_add(accH[g][n]);
            if (lane == 0) {
                red[wid][g * 4 + n] = vI;
                red[wid][12 + g * 4 + n] = vH;
            }
        }
    }
    __syncthreads();

    if (t < 4) {
        int n = t;
        float I[3], H[3];
#pragma unroll
        for (int g = 0; g < 3; g++) {
            I[g] = red[0][g * 4 + n] + red[1][g * 4 + n] + red[2][g * 4 + n] + red[3][g * 4 + n];
            H[g] = red[0][12 + g * 4 + n] + red[1][12 + g * 4 + n] + red[2][12 + g * 4 + n] + red[3][12 + g * 4 + n];
        }
        float r = 1.f / (1.f + expf(-(I[0] + H[0])));
        float z = 1.f / (1.f + expf(-(I[1] + H[1])));
        float nn = tanhf(I[2] + r * H[2]);
        float hv = ((const float*)hcur)[c * 4 + n];
        ((float*)hnext)[c * 4 + n] = (1.f - z) * nn + z * hv;
    }
}

__global__ void enc_k(const float4* __restrict__ h, float* __restrict__ enc) {
    int idx = blockIdx.x * 256 + threadIdx.x;  // 0..16383
    int n = idx >> 12;
    int k = idx & (S - 1);
    enc[idx] = ((const float*)h)[k * 4 + n];
}

__global__ __launch_bounds__(256) void fc1_k(const float* __restrict__ W, const float* __restrict__ b,
                                             const float* __restrict__ enc, float* __restrict__ x1) {
    int j = blockIdx.x, t = threadIdx.x;
    const float4* row = (const float4*)(W + (size_t)j * (4 * S));
    const float4* e4 = (const float4*)enc;
    float acc = 0.f;
#pragma unroll 4
    for (int i = 0; i < 16; i++) {
        int m = t + 256 * i;  // 0..4095 float4 idx
        float4 w = row[m];
        float4 e = e4[m];
        acc += w.x * e.x + w.y * e.y + w.z * e.z + w.w * e.w;
    }
    acc = wave_reduce_add(acc);
    __shared__ float red[4];
    if ((t & 63) == 0) red[t >> 6] = acc;
    __syncthreads();
    if (t == 0) x1[j] = red[0] + red[1] + red[2] + red[3] + b[j];
}

__global__ __launch_bounds__(256) void fc2_k(const float* __restrict__ W, const float* __restrict__ b,
                                             const float* __restrict__ x1, float* __restrict__ out) {
    int t = threadIdx.x;
    const float4* x4 = (const float4*)x1;
    const float4* w0 = (const float4*)W;
    const float4* w1 = (const float4*)(W + S);
    float a0 = 0.f, a1 = 0.f;
#pragma unroll
    for (int i = 0; i < 4; i++) {
        int m = t + 256 * i;  // 0..1023
        float4 x = x4[m];
        float4 u = w0[m];
        float4 v = w1[m];
        a0 += u.x * x.x + u.y * x.y + u.z * x.z + u.w * x.w;
        a1 += v.x * x.x + v.y * x.y + v.z * x.z + v.w * x.w;
    }
    a0 = wave_reduce_add(a0);
    a1 = wave_reduce_add(a1);
    __shared__ float red0[4], red1[4];
    int lane = t & 63, wid = t >> 6;
    if (lane == 0) { red0[wid] = a0; red1[wid] = a1; }
    __syncthreads();
    if (t == 0) {
        float l0 = red0[0] + red0[1] + red0[2] + red0[3] + b[0];
        float l1 = red1[0] + red1[1] + red1[2] + red1[3] + b[1];
        float m = fmaxf(l0, l1);
        float ls = m + logf(expf(l0 - m) + expf(l1 - m));
        out[0] = l0 - ls;
        out[1] = l1 - ls;
    }
}

extern "C" void kernel_launch(void* const* d_in, const int* in_sizes, int n_in,
                              void* d_out, int out_size, void* d_ws, size_t ws_size,
                              hipStream_t stream) {
    const float* A_out = (const float*)d_in[0];
    const float* A_in  = (const float*)d_in[1];
    const float* ann   = (const float*)d_in[2];
    const float* W_ih  = (const float*)d_in[3];
    const float* W_hh  = (const float*)d_in[4];
    const float* fc1_w = (const float*)d_in[5];
    const float* fc1_b = (const float*)d_in[6];
    const float* fc2_w = (const float*)d_in[7];
    const float* fc2_b = (const float*)d_in[8];
    float* out = (float*)d_out;

    float* ws_f = (float*)d_ws;
    float4* hA  = (float4*)ws_f;          // 4096 float4
    float4* hB  = hA + S;                 // 4096 float4
    float4* a_t = hB + S;                 // 8192 float4
    float* enc  = (float*)(a_t + 2 * S);  // 16384 floats
    float* x1   = enc + 4 * S;            // 4096 floats

    init_h_k<<<S / 256, 256, 0, stream>>>(ann, hA);

    for (int step = 0; step < 8; step++) {
        float4* cur = (step & 1) ? hB : hA;
        float4* nxt = (step & 1) ? hA : hB;
        compute_a_k<<<2 * S / 256, 256, 0, stream>>>(A_out, A_in, cur, a_t);
        gru_col_k<<<S, 256, 0, stream>>>(W_ih, W_hh, a_t, cur, nxt);
    }
    // After 8 steps the final state is back in hA.
    enc_k<<<4 * S / 256, 256, 0, stream>>>(hA, enc);
    fc1_k<<<S, 256, 0, stream>>>(fc1_w, fc1_b, enc, x1);
    fc2_k<<<1, 256, 0, stream>>>(fc2_w, fc2_b, x1, out);
}